// Round 1
// baseline (2094.580 us; speedup 1.0000x reference)
//
#include <hip/hip_runtime.h>
#include <hip/hip_fp16.h>

#define TSEQ  2048
#define BATCH 64
#define DIN   128
#define DH    256
#define WSTR  384   // W row stride = dimIn + dimH

typedef __fp16 h2 __attribute__((ext_vector_type(2)));

#if defined(__has_builtin)
#if __has_builtin(__builtin_amdgcn_fdot2)
#define HAVE_FDOT2 1
#endif
#endif

static __device__ __forceinline__ h2 bc_h2(unsigned int u) {
    return __builtin_bit_cast(h2, u);
}

// ---------------- Phase 1: xw = x @ Wx^T + b, written into d_out ----------------
// grid: (BT/32, 256/64), block: 256 threads. Tile 32 rows x 64 cols, K=128.
__global__ __launch_bounds__(256) void xw_gemm(const float* __restrict__ x,
                                               const float* __restrict__ W,
                                               const float* __restrict__ bias,
                                               float* __restrict__ out) {
    __shared__ float xs[32][132];   // stride 132: float4-store aligned (528B%16==0), read banks (4r+k)%32 spread
    __shared__ float ws[64][129];   // stride 129 (odd): scalar reads -> 2-way conflict only (free)

    const int tid = threadIdx.x;
    const int R0 = blockIdx.x * 32;
    const int C0 = blockIdx.y * 64;

    // load x tile: 32 rows x 128 k = 1024 float4, coalesced
    {
        const float4* x4 = (const float4*)x;
        int idx = tid;
#pragma unroll
        for (int q = 0; q < 4; ++q, idx += 256) {
            int r  = idx >> 5;      // 32 float4 per row
            int kq = idx & 31;
            float4 f = x4[(size_t)(R0 + r) * 32 + kq];
            *(float4*)&xs[r][kq * 4] = f;
        }
    }
    // load Wx tile: 64 cols x 128 k = 2048 float4, coalesced along k
    {
        const float4* W4 = (const float4*)W;   // row stride 96 float4
        int idx = tid;
#pragma unroll
        for (int q = 0; q < 8; ++q, idx += 256) {
            int c  = idx >> 5;
            int kq = idx & 31;
            float4 f = W4[(size_t)(C0 + c) * 96 + kq];   // k = 4*kq < 128 -> Wx part
            ws[c][kq * 4 + 0] = f.x;
            ws[c][kq * 4 + 1] = f.y;
            ws[c][kq * 4 + 2] = f.z;
            ws[c][kq * 4 + 3] = f.w;
        }
    }
    __syncthreads();

    const int cx = (tid & 15) * 4;   // 4 consecutive cols
    const int r2 = tid >> 4;         // rows r2 and r2+16
    float a00 = 0.f, a01 = 0.f, a02 = 0.f, a03 = 0.f;
    float a10 = 0.f, a11 = 0.f, a12 = 0.f, a13 = 0.f;

#pragma unroll 4
    for (int k = 0; k < 128; ++k) {
        float xa = xs[r2][k];
        float xb = xs[r2 + 16][k];
        float w0 = ws[cx + 0][k];
        float w1 = ws[cx + 1][k];
        float w2 = ws[cx + 2][k];
        float w3 = ws[cx + 3][k];
        a00 = fmaf(xa, w0, a00); a01 = fmaf(xa, w1, a01);
        a02 = fmaf(xa, w2, a02); a03 = fmaf(xa, w3, a03);
        a10 = fmaf(xb, w0, a10); a11 = fmaf(xb, w1, a11);
        a12 = fmaf(xb, w2, a12); a13 = fmaf(xb, w3, a13);
    }

    float4 bi = *(const float4*)&bias[C0 + cx];
    float4 o0 = {a00 + bi.x, a01 + bi.y, a02 + bi.z, a03 + bi.w};
    float4 o1 = {a10 + bi.x, a11 + bi.y, a12 + bi.z, a13 + bi.w};
    *(float4*)&out[(size_t)(R0 + r2) * DH + C0 + cx] = o0;
    *(float4*)&out[(size_t)(R0 + r2 + 16) * DH + C0 + cx] = o1;
}

// ---------------- Phase 2: sequential scan, one block per batch ----------------
// Thread j owns output j; Wh row j lives in 128 VGPRs as packed fp16 pairs.
// h double-buffered in LDS (fp16); one barrier per step.
__global__ __launch_bounds__(256, 1) void rnn_scan(const float* __restrict__ W,
                                                   const float* __restrict__ h0,
                                                   float* __restrict__ out) {
    __shared__ __align__(16) __fp16 hbuf[2][DH];

    const int j = threadIdx.x;
    const int b = blockIdx.x;

    // load Wh row j -> 128 packed fp16 pairs
    h2 w[DH / 2];
    {
        const float4* Wr = (const float4*)(W + (size_t)j * WSTR + DIN);
#pragma unroll
        for (int q = 0; q < 64; ++q) {
            float4 f = Wr[q];
            w[2 * q]     = h2{(__fp16)f.x, (__fp16)f.y};
            w[2 * q + 1] = h2{(__fp16)f.z, (__fp16)f.w};
        }
    }

    hbuf[0][j] = (__fp16)h0[(size_t)b * DH + j];

    float* orow = out + (size_t)b * TSEQ * DH + j;   // column j of this batch's rows
    float xw_cur = orow[0];                          // xw for t=0 (written by phase 1)
    __syncthreads();

    int p = 0;
    for (int t = 0; t < TSEQ; ++t) {
        float xw_nxt = 0.f;
        if (t + 1 < TSEQ) xw_nxt = orow[(size_t)(t + 1) * DH];   // prefetch next step's xw

        const uint4* hp = (const uint4*)hbuf[p];
        float a0 = 0.f, a1 = 0.f, a2 = 0.f, a3 = 0.f;
        float a4 = 0.f, a5 = 0.f, a6 = 0.f, a7 = 0.f;

#ifdef HAVE_FDOT2
#pragma unroll
        for (int c = 0; c < 16; ++c) {
            uint4 v0 = hp[2 * c];       // broadcast ds_read_b128 (all lanes same addr)
            uint4 v1 = hp[2 * c + 1];
            a0 = __builtin_amdgcn_fdot2(w[8 * c + 0], bc_h2(v0.x), a0, false);
            a1 = __builtin_amdgcn_fdot2(w[8 * c + 1], bc_h2(v0.y), a1, false);
            a2 = __builtin_amdgcn_fdot2(w[8 * c + 2], bc_h2(v0.z), a2, false);
            a3 = __builtin_amdgcn_fdot2(w[8 * c + 3], bc_h2(v0.w), a3, false);
            a4 = __builtin_amdgcn_fdot2(w[8 * c + 4], bc_h2(v1.x), a4, false);
            a5 = __builtin_amdgcn_fdot2(w[8 * c + 5], bc_h2(v1.y), a5, false);
            a6 = __builtin_amdgcn_fdot2(w[8 * c + 6], bc_h2(v1.z), a6, false);
            a7 = __builtin_amdgcn_fdot2(w[8 * c + 7], bc_h2(v1.w), a7, false);
        }
#else
#pragma unroll
        for (int c = 0; c < 32; ++c) {
            uint4 v = hp[c];
            h2 hh0 = bc_h2(v.x), hh1 = bc_h2(v.y), hh2 = bc_h2(v.z), hh3 = bc_h2(v.w);
            h2 w0 = w[4 * c + 0], w1 = w[4 * c + 1], w2 = w[4 * c + 2], w3 = w[4 * c + 3];
            a0 = fmaf((float)w0.x, (float)hh0.x, a0);
            a1 = fmaf((float)w0.y, (float)hh0.y, a1);
            a2 = fmaf((float)w1.x, (float)hh1.x, a2);
            a3 = fmaf((float)w1.y, (float)hh1.y, a3);
            a4 = fmaf((float)w2.x, (float)hh2.x, a4);
            a5 = fmaf((float)w2.y, (float)hh2.y, a5);
            a6 = fmaf((float)w3.x, (float)hh3.x, a6);
            a7 = fmaf((float)w3.y, (float)hh3.y, a7);
        }
#endif
        float pre = xw_cur + (((a0 + a1) + (a2 + a3)) + ((a4 + a5) + (a6 + a7)));
        // tanh(x) = 1 - 2/(e^(2x)+1); saturates correctly for |x| large
        float e  = __expf(2.0f * pre);
        float hn = 1.0f - 2.0f * __builtin_amdgcn_rcpf(e + 1.0f);

        hbuf[p ^ 1][j] = (__fp16)hn;
        __syncthreads();
        // store after the barrier: its vmcnt drain hides until the NEXT barrier
        orow[(size_t)t * DH] = hn;

        xw_cur = xw_nxt;
        p ^= 1;
    }
}

extern "C" void kernel_launch(void* const* d_in, const int* in_sizes, int n_in,
                              void* d_out, int out_size, void* d_ws, size_t ws_size,
                              hipStream_t stream) {
    const float* x    = (const float*)d_in[0];
    const float* h0   = (const float*)d_in[1];
    const float* W    = (const float*)d_in[2];
    const float* bias = (const float*)d_in[3];
    float* out = (float*)d_out;

    dim3 g1(BATCH * TSEQ / 32, DH / 64);
    xw_gemm<<<g1, 256, 0, stream>>>(x, W, bias, out);
    rnn_scan<<<BATCH, 256, 0, stream>>>(W, h0, out);
}